// Round 8
// baseline (879.517 us; speedup 1.0000x reference)
//
#include <hip/hip_runtime.h>

#define SS 1024
#define BB 2048
#define NT 512     // 8 waves: wv = dir + 2*wq  (dir = wv&1, wq = wv>>1)
#define GRID 512   // 4 batches/block; 2 blocks/CU -> 4 waves/SIMD
#define G4 4

typedef unsigned int u32;
typedef unsigned short u16;
typedef _Float16 f16x4 __attribute__((ext_vector_type(4)));
typedef _Float16 f16x8 __attribute__((ext_vector_type(8)));
typedef float f32x4 __attribute__((ext_vector_type(4)));
typedef u32 u32x2v __attribute__((ext_vector_type(2)));
typedef u32 u32x4v __attribute__((ext_vector_type(4)));
typedef __fp16 fp16x2 __attribute__((ext_vector_type(2)));

#define L2E 1.4426950408889634f

// lgkmcnt drain + barrier (vmcnt NOT drained: x prefetch stays in flight)
#define BARRIER() asm volatile("s_waitcnt lgkmcnt(0)\n\ts_barrier" ::: "memory")

#if __has_builtin(__builtin_amdgcn_mfma_f32_16x16x32_f16)
#define HAS32 1
#else
#define HAS32 0
#endif

// ---------- helpers ----------
__device__ __forceinline__ u16 f2bf(float f) {
  u32 u = __float_as_uint(f);
  return (u16)((u + 0x7fffu + ((u >> 16) & 1u)) >> 16);
}
template<bool BFM>
__device__ __forceinline__ float ldin(const void* p, int i) {
  if (BFM) { u16 v = ((const u16*)p)[i]; return __uint_as_float(((u32)v) << 16); }
  return ((const float*)p)[i];
}
__device__ __forceinline__ u32 packrtz(float lo, float hi) {
#if __has_builtin(__builtin_amdgcn_cvt_pkrtz)
  fp16x2 h = __builtin_amdgcn_cvt_pkrtz(lo, hi);
  return __builtin_bit_cast(u32, h);
#else
  _Float16 ha = (_Float16)lo, hb = (_Float16)hi;
  return (u32)__builtin_bit_cast(u16, ha) | ((u32)__builtin_bit_cast(u16, hb) << 16);
#endif
}
template<bool BFM>
__device__ __forceinline__ u32 ldpacks(const void* p, int i, float s) {
  float a, b;
  if (BFM) {
    u32 pr = *(const u32*)((const u16*)p + i);
    a = __uint_as_float(pr << 16);
    b = __uint_as_float(pr & 0xffff0000u);
  } else {
    a = ((const float*)p)[i];
    b = ((const float*)p)[i + 1];
  }
  return packrtz(a * s, b * s);
}
__device__ __forceinline__ float exp2fast(float x) {
#if __has_builtin(__builtin_amdgcn_exp2f)
  return __builtin_amdgcn_exp2f(x);
#else
  return __expf(x * 0.6931471805599453f);
#endif
}
// pre-acts PRE-SCALED: sigmoid gates by -log2e, tanh gate by +2log2e
__device__ __forceinline__ float combine(const float acc[4], float& c) {
  float ig = __builtin_amdgcn_rcpf(1.0f + exp2fast(acc[0]));
  float fg = __builtin_amdgcn_rcpf(1.0f + exp2fast(acc[1]));
  float gg = 1.0f - 2.0f * __builtin_amdgcn_rcpf(1.0f + exp2fast(acc[2]));
  float og = __builtin_amdgcn_rcpf(1.0f + exp2fast(acc[3]));
  c = fg * c + ig * gg;
  float th = 1.0f - 2.0f * __builtin_amdgcn_rcpf(1.0f + exp2fast((2.0f * L2E) * c));
  return og * th;
}
__device__ __forceinline__ f32x4 mfma16(f16x4 a, f16x4 b, f32x4 c) {
  return __builtin_amdgcn_mfma_f32_16x16x16f16(a, b, c, 0, 0, 0);
}
#if HAS32
__device__ __forceinline__ f32x4 mfma32(f16x8 a, f16x8 b, f32x4 c) {
  return __builtin_amdgcn_mfma_f32_16x16x32_f16(a, b, c, 0, 0, 0);
}
#endif
__device__ __forceinline__ u16 f16bits(float x) {
  _Float16 h = (_Float16)x;
  return __builtin_bit_cast(u16, h);
}

// LDS (batch-major rows, stride 24 dw = 96 B: b128-aligned, <=2-way banks):
//  h0l : [dir][par][4 rows][24 dw]   (f16 h, 32 cells in first 16 dw)
//  hf1l: [par][4 rows][24 dw]
//  po  : [par][8 wave][4 batch] f32 head partials
//
// Duty spread (B cols duplicated x4: col m = batch m&3):
//  lane (m,q) of wave (dir,wq): bM=m&3, tsel=(m>>2)&1, lsel=m>>3
//  tile T = 2wq+tsel -> cell = 8wq+4tsel+q; lsel=0 -> L0 combine, 1 -> L1.
// Schedule (ONE barrier/iter), same skew as R6/R7:
//  L0 t=u (fwd)/u-1 (bwd); L1 t=u-1 (fwd)/u-2 (bwd); head t=u-2; emit t=u-3.
template<bool BFM>
__device__ __forceinline__ void run(
    const void* xg,
    const void* Wih_f0, const void* Whh_f0, const void* b_f0,
    const void* Wih_f1, const void* Whh_f1, const void* b_f1,
    const void* Wih_b0, const void* Whh_b0, const void* b_b0,
    const void* Wih_b1, const void* Whh_b1, const void* b_b1,
    const void* Wlin, const void* blin, const int* futp, void* outp_g,
    u32* h0l, u32* hf1l, float* po, int tid, int bid) {
  const int wv = tid >> 6, lane = tid & 63;
  const int dirv = wv & 1, wq = wv >> 1;
  const int m = lane & 15, q = lane >> 4;
  const int bM = m & 3, tsel = (m >> 2) & 1, lsel = m >> 3;
  const int cellM = 8 * wq + 4 * tsel + q;
  const int gb4 = bid * G4;
  const int xb = gb4 + bM;

  const void* s0  = dirv ? Whh_b0 : Whh_f0;
  const void* sA  = dirv ? Wih_b1 : Wih_f1;
  const void* sB  = dirv ? Whh_b1 : Whh_f1;
  const void* pb0 = dirv ? b_b0 : b_f0;
  const void* pb1 = dirv ? b_b1 : b_f1;
  const void* pwx = dirv ? Wih_b0 : Wih_f0;

  // ---- A-fragments, cell-major row permutation W~[cell*4+gate]=W[gate*32+cell]
  // A row = m -> R~ = 16T+m -> gate=m&3, cell=4T+(m>>2). Same sigma for A and B.
  const float sw = ((m & 3) == 2) ? (2.0f * L2E) : (-L2E);
#if HAS32
  f16x8 w0f[2], w1i[2], w1r[2];   // [tile]; K=32 frag: sigma(q,j)=8q+j
#pragma unroll
  for (int t = 0; t < 2; ++t) {
    const int R = (m & 3) * 32 + 4 * (2 * wq + t) + (m >> 2);
    const int i0 = R * 32 + 8 * q;
    u32x4v v;
    v.x = ldpacks<BFM>(s0, i0 + 0, sw); v.y = ldpacks<BFM>(s0, i0 + 2, sw);
    v.z = ldpacks<BFM>(s0, i0 + 4, sw); v.w = ldpacks<BFM>(s0, i0 + 6, sw);
    w0f[t] = __builtin_bit_cast(f16x8, v);
    v.x = ldpacks<BFM>(sA, i0 + 0, sw); v.y = ldpacks<BFM>(sA, i0 + 2, sw);
    v.z = ldpacks<BFM>(sA, i0 + 4, sw); v.w = ldpacks<BFM>(sA, i0 + 6, sw);
    w1i[t] = __builtin_bit_cast(f16x8, v);
    v.x = ldpacks<BFM>(sB, i0 + 0, sw); v.y = ldpacks<BFM>(sB, i0 + 2, sw);
    v.z = ldpacks<BFM>(sB, i0 + 4, sw); v.w = ldpacks<BFM>(sB, i0 + 6, sw);
    w1r[t] = __builtin_bit_cast(f16x8, v);
  }
#else
  f16x4 w0f[2][2], w1i[2][2], w1r[2][2];  // x16 frags: sigma(s,q,j)=16s+4q+j
#pragma unroll
  for (int t = 0; t < 2; ++t) {
    const int R = (m & 3) * 32 + 4 * (2 * wq + t) + (m >> 2);
#pragma unroll
    for (int s = 0; s < 2; ++s) {
      const int i0 = R * 32 + 16 * s + 4 * q;
      u32x2v v;
      v.x = ldpacks<BFM>(s0, i0, sw); v.y = ldpacks<BFM>(s0, i0 + 2, sw);
      w0f[t][s] = __builtin_bit_cast(f16x4, v);
      v.x = ldpacks<BFM>(sA, i0, sw); v.y = ldpacks<BFM>(sA, i0 + 2, sw);
      w1i[t][s] = __builtin_bit_cast(f16x4, v);
      v.x = ldpacks<BFM>(sB, i0, sw); v.y = ldpacks<BFM>(sB, i0 + 2, sw);
      w1r[t][s] = __builtin_bit_cast(f16x4, v);
    }
  }
#endif
  // ---- duty constants: ONE (cell, layer) per lane ----
  float bv[4], wxv[4];
  const void* pbL = lsel ? pb1 : pb0;
#pragma unroll
  for (int r = 0; r < 4; ++r) {
    const float sg = (r == 2) ? (2.0f * L2E) : (-L2E);
    bv[r] = ldin<BFM>(pbL, r * 32 + cellM) * sg;
    wxv[r] = lsel ? 0.f : ldin<BFM>(pwx, r * 32 + cellM) * sg;
  }
  const float wlM = lsel ? ldin<BFM>(Wlin, dirv * 32 + cellM) : 0.f;
  const float blv = ldin<BFM>(blin, 0);
  const int fut = *futp;

  // zero LDS
  for (int i = tid; i < 2 * 2 * 4 * 24; i += NT) h0l[i] = 0u;
  for (int i = tid; i < 2 * 4 * 24; i += NT) hf1l[i] = 0u;
  if (tid < 64) po[tid] = 0.f;
  __syncthreads();

  float cS = 0.f, pr = 0.f;
  float x_cur = ldin<BFM>(xg, (dirv ? ((fut + 1) & (SS - 1)) : 0) * BB + xb);

  for (int u = 0; u <= SS + 2; ++u) {
    const int par_w = u & 1, par_r = (u + 1) & 1;
    const int nidx = dirv ? ((fut - u) & (SS - 1)) : ((u + 1 < SS) ? u + 1 : SS - 1);
    const float x_nxt = ldin<BFM>(xg, nidx * BB + xb);  // in flight across barrier

    f32x4 z = {0.f, 0.f, 0.f, 0.f};
    f32x4 a0, a1, d0, d1;
#if HAS32
    // ---- B-frags: one b128 each; h0(prev) feeds L0-rec AND L1-inp ----
    const u32x4v* hbp = (const u32x4v*)&h0l[((dirv * 2 + par_r) * 4 + bM) * 24];
    const u32x4v* hrp = (const u32x4v*)&hf1l[(par_r * 4 + bM) * 24];
    f16x8 Bs = __builtin_bit_cast(f16x8, hbp[q]);   // cells 8q..8q+7
    f16x8 Br = __builtin_bit_cast(f16x8, hrp[q]);
    a0 = mfma32(w0f[0], Bs, z);
    a1 = mfma32(w0f[1], Bs, z);
    d0 = mfma32(w1r[0], Br, mfma32(w1i[0], Bs, z));
    d1 = mfma32(w1r[1], Br, mfma32(w1i[1], Bs, z));
#else
    const u32x2v* hbp = (const u32x2v*)&h0l[((dirv * 2 + par_r) * 4 + bM) * 24];
    const u32x2v* hrp = (const u32x2v*)&hf1l[(par_r * 4 + bM) * 24];
    a0 = z; a1 = z; d0 = z; d1 = z;
#pragma unroll
    for (int s = 0; s < 2; ++s) {
      f16x4 B = __builtin_bit_cast(f16x4, hbp[4 * s + q]);
      a0 = mfma16(w0f[0][s], B, a0);
      a1 = mfma16(w0f[1][s], B, a1);
      d0 = mfma16(w1i[0][s], B, d0);
      d1 = mfma16(w1i[1][s], B, d1);
    }
#pragma unroll
    for (int s = 0; s < 2; ++s) {
      f16x4 B = __builtin_bit_cast(f16x4, hrp[4 * s + q]);
      d0 = mfma16(w1r[0][s], B, d0);
      d1 = mfma16(w1r[1][s], B, d1);
    }
#endif

    // ---- head finalize (wave 0): emit out(u-3) from po[par_r] ----
    if (wv == 0 && u >= 3) {
      float pz = po[par_r * 32 + (lane & 31)];   // [w=lane>>2][b=lane&3]
      pz += __shfl_xor(pz, 4, 64);
      pz += __shfl_xor(pz, 8, 64);
      pz += __shfl_xor(pz, 16, 64);
      if (lane < 4) {
        float o = pz + blv;
        size_t pos = (size_t)(gb4 + lane) * SS + (size_t)(u - 3);
        if (BFM) ((u16*)outp_g)[pos] = f2bf(o);
        else     ((float*)outp_g)[pos] = o;
      }
    }

    // ---- single combine per lane: select own (tile, layer) quad ----
    float acc[4];
#pragma unroll
    for (int r = 0; r < 4; ++r) {
      float sA_ = tsel ? a1[r] : a0[r];
      float sD_ = tsel ? d1[r] : d0[r];
      float sel = lsel ? sD_ : sA_;
      acc[r] = sel + fmaf(wxv[r], x_cur, bv[r]);   // wxv=0 for L1 lanes
    }
    float hn = combine(acc, cS);
    // warm-up garbage resets (skewed starts)
    bool junk = lsel ? (dirv ? (u <= 1) : (u == 0)) : (dirv && (u == 0));
    if (junk) { cS = 0.f; if (!lsel) hn = 0.f; }

    if (!lsel) {          // L0 lanes publish h0(t) -> par_w
      ((u16*)&h0l[((dirv * 2 + par_w) * 4 + bM) * 24])[cellM] = f16bits(hn);
    } else if (!dirv && u >= 1) {   // fwd L1 lanes publish hf1(u-1) -> par_w
      ((u16*)&hf1l[(par_w * 4 + bM) * 24])[cellM] = f16bits(hn);
    }

    // ---- head partials for t=u-2: fwd uses hf1(u-2) (carry), bwd hb1(u-2) ----
    float v = wlM * (dirv ? hn : pr);   // wlM=0 on L0 lanes
    pr = hn;
    v += __shfl_xor(v, 4, 64);    // sum over tsel
    v += __shfl_xor(v, 16, 64);   // sum over q
    v += __shfl_xor(v, 32, 64);
    if (lane >= 8 && lane < 12) po[par_w * 32 + wv * 4 + (lane - 8)] = v;

    BARRIER();
    x_cur = x_nxt;
  }
}

// 512 thr (8 waves), min 4 waves/EU -> 128-VGPR cap; GRID=512 -> 2 blocks/CU
// = 16 waves/CU = 4 waves/SIMD.
__global__ void __launch_bounds__(NT, 4) lstm_kernel(
    const void* __restrict__ xg,
    const void* Wih_f0, const void* Whh_f0, const void* b_f0,
    const void* Wih_f1, const void* Whh_f1, const void* b_f1,
    const void* Wih_b0, const void* Whh_b0, const void* b_b0,
    const void* Wih_b1, const void* Whh_b1, const void* b_b1,
    const void* Wlin, const void* blin, const int* __restrict__ futp,
    void* __restrict__ outp) {
  __shared__ __align__(16) u32 h0s[2 * 2 * 4 * 24];
  __shared__ __align__(16) u32 hf1s[2 * 4 * 24];
  __shared__ __align__(16) float pos_[2 * 32];

  // dtype detection (uniform): bf16-pairs read as fp32 implausible as N(0,1)
  bool bfm;
  {
    const float* xf = (const float*)xg;
    int bad = 0;
    for (int i = 0; i < 64; ++i) {
      float a = fabsf(xf[i]);
      bool ok = (a == 0.0f) || (a > 1e-8f && a < 1e4f);
      if (!ok) bad = 1;
    }
    bfm = (bad != 0);
  }

  if (bfm)
    run<true>(xg, Wih_f0, Whh_f0, b_f0, Wih_f1, Whh_f1, b_f1,
              Wih_b0, Whh_b0, b_b0, Wih_b1, Whh_b1, b_b1,
              Wlin, blin, futp, outp, h0s, hf1s, pos_,
              threadIdx.x, blockIdx.x);
  else
    run<false>(xg, Wih_f0, Whh_f0, b_f0, Wih_f1, Whh_f1, b_f1,
               Wih_b0, Whh_b0, b_b0, Wih_b1, Whh_b1, b_b1,
               Wlin, blin, futp, outp, h0s, hf1s, pos_,
               threadIdx.x, blockIdx.x);
}

extern "C" void kernel_launch(void* const* d_in, const int* in_sizes, int n_in,
                              void* d_out, int out_size, void* d_ws, size_t ws_size,
                              hipStream_t stream) {
  (void)in_sizes; (void)n_in; (void)out_size; (void)d_ws; (void)ws_size;
  lstm_kernel<<<dim3(GRID), dim3(NT), 0, stream>>>(
      d_in[0], d_in[1], d_in[2], d_in[3], d_in[4], d_in[5], d_in[6],
      d_in[7], d_in[8], d_in[9], d_in[10], d_in[11], d_in[12],
      d_in[13], d_in[14], (const int*)d_in[15], d_out);
}